// Round 3
// baseline (1009.009 us; speedup 1.0000x reference)
//
#include <hip/hip_runtime.h>
#include <hip/hip_bf16.h>

#define HID 256
#define HEADS 8
#define HDIM 32
#define BATCH 2
#define SEQ 2048
#define MROWS (BATCH*SEQ)   // 4096

// ---------------------------------------------------------------------------
// Mask dtype detection: scan first 8.4MB (= min possible mask buffer size) as
// u32 words. int32 mask words are {0,1}; fp32 mask words are {0,0x3F800000};
// a byte mask at 5% density is certain to produce words outside that set.
// flag!=0  =>  byte mask.
// ---------------------------------------------------------------------------
__global__ __launch_bounds__(256) void detect_mask(const unsigned* __restrict__ m,
                                                   unsigned* __restrict__ flag)
{
    unsigned bad = 0;
    for (size_t i = (size_t)blockIdx.x * 256 + threadIdx.x; i < 2097152u;
         i += (size_t)gridDim.x * 256) {
        const unsigned wv = m[i];
        if (wv != 0u && wv != 1u && wv != 0x3F800000u) bad = 1;
    }
    if (__ballot(bad)) {
        if ((threadIdx.x & 63) == 0) atomicOr(flag, 1u);
    }
}

// Compact per-(b,q) row adjacency into index lists (order irrelevant).
__global__ __launch_bounds__(256) void build_idx(const void* __restrict__ mask,
                                                 const unsigned* __restrict__ flag,
                                                 int* __restrict__ counts,
                                                 unsigned short* __restrict__ idx)
{
    const int row = blockIdx.x;          // b*SEQ + q
    __shared__ int cnt;
    if (threadIdx.x == 0) cnt = 0;
    __syncthreads();
    const int bytemode = (*flag != 0);
    unsigned short* dst = idx + ((size_t)row << 11);
    for (int k = threadIdx.x; k < SEQ; k += 256) {
        int set;
        if (bytemode) set = ((const unsigned char*)mask)[((size_t)row << 11) + k] != 0;
        else          set = ((const unsigned*)mask)[((size_t)row << 11) + k] != 0u;
        if (set) {
            const int p = atomicAdd(&cnt, 1);
            dst[p] = (unsigned short)k;
        }
    }
    __syncthreads();
    if (threadIdx.x == 0) counts[row] = cnt;
}

// ---------------------------------------------------------------------------
// LayerNorm: one 256-thread block per row of 256.
// ---------------------------------------------------------------------------
__global__ __launch_bounds__(256) void ln256(const float* __restrict__ in,
                                             const float* __restrict__ g,
                                             const float* __restrict__ b,
                                             float* __restrict__ out)
{
    const int row = blockIdx.x, tid = threadIdx.x;
    __shared__ float red[256];
    const float v = in[((size_t)row << 8) + tid];
    red[tid] = v; __syncthreads();
    for (int s = 128; s > 0; s >>= 1) {
        if (tid < s) red[tid] += red[tid + s];
        __syncthreads();
    }
    const float m = red[0] * (1.f/HID);
    __syncthreads();
    const float dv = v - m;
    red[tid] = dv * dv; __syncthreads();
    for (int s = 128; s > 0; s >>= 1) {
        if (tid < s) red[tid] += red[tid + s];
        __syncthreads();
    }
    const float var = red[0] * (1.f/HID);
    out[((size_t)row << 8) + tid] = dv * rsqrtf(var + 1e-5f) * g[tid] + b[tid];
}

// ---------------------------------------------------------------------------
// fp32 GEMM: C[M x N] = A[M x KTOT] @ W[KTOT x N] + bias, epilogue variants.
// Block = 256 threads handles 16 rows; cols chunked by 256; K chunked by 256.
// EPI 0: scatter to (B,H,S,D) layout (QKV).   EPI 1: + res -> out (Wo, W2).
// EPI 2: exact GELU -> out (W1).
// ---------------------------------------------------------------------------
template<int KTOT, int EPI>
__global__ __launch_bounds__(256) void gemm16(const float* __restrict__ A,
                                              const float* __restrict__ W,
                                              const float* __restrict__ bias,
                                              const float* __restrict__ res,
                                              float* __restrict__ out,
                                              int N)
{
    __shared__ float a[16][256];
    const int tid = threadIdx.x;
    const int r0 = blockIdx.x * 16;
    for (int c0 = 0; c0 < N; c0 += 256) {
        const int c = c0 + tid;
        float acc[16];
#pragma unroll
        for (int r = 0; r < 16; ++r) acc[r] = 0.f;
        for (int kc = 0; kc < KTOT; kc += 256) {
            __syncthreads();
#pragma unroll 4
            for (int i = tid; i < 16*256; i += 256)
                a[i >> 8][i & 255] = A[(size_t)(r0 + (i >> 8)) * KTOT + kc + (i & 255)];
            __syncthreads();
            for (int k = 0; k < 256; k += 4) {
                const size_t wb = (size_t)(kc + k) * N + c;
                const float w0 = W[wb];
                const float w1 = W[wb + (size_t)N];
                const float w2 = W[wb + 2*(size_t)N];
                const float w3 = W[wb + 3*(size_t)N];
#pragma unroll
                for (int r = 0; r < 16; ++r) {
                    const float4 av = *(const float4*)(&a[r][k]);
                    acc[r] = fmaf(av.x, w0, acc[r]);
                    acc[r] = fmaf(av.y, w1, acc[r]);
                    acc[r] = fmaf(av.z, w2, acc[r]);
                    acc[r] = fmaf(av.w, w3, acc[r]);
                }
            }
        }
        const float bv = bias[c];
#pragma unroll
        for (int r = 0; r < 16; ++r) {
            const int row = r0 + r;
            const float v = acc[r] + bv;
            if (EPI == 0) {
                const int bb = row >> 11, s = row & 2047, h = c >> 5, d = c & 31;
                out[(((size_t)(bb * HEADS + h) * SEQ + s) << 5) + d] = v;
            } else if (EPI == 1) {
                const size_t o = (size_t)row * N + c;
                out[o] = v + res[o];
            } else {
                const size_t o = (size_t)row * N + c;
                out[o] = 0.5f * v * (1.0f + erff(v * 0.70710678118654752f));
            }
        }
    }
}

// ---------------------------------------------------------------------------
// Sparse masked attention. One wave per (b,h,q) row; 4 waves per block.
// Half-waves process alternate nonzero key indices; 32-lane dot reduce;
// scores in LDS; wave softmax; gather-weighted V accumulate.
// Masked entries: reference gives exp(-1e9 - mx) == 0 exactly in fp32, so
// restricting to the unmasked index list is exact.
// ---------------------------------------------------------------------------
__global__ __launch_bounds__(256) void attn_sparse(const float* __restrict__ Q,
                                                   const float* __restrict__ K,
                                                   const float* __restrict__ V,
                                                   const unsigned short* __restrict__ idx,
                                                   const int* __restrict__ counts,
                                                   float* __restrict__ out)
{
    __shared__ float sc[4][2048];
    const int tid  = threadIdx.x;
    const int wave = tid >> 6, lane = tid & 63;
    const int r = blockIdx.x * 4 + wave;             // (b*H + h)*SEQ + q
    const int b = r >> 14, h = (r >> 11) & 7, q = r & 2047;
    const int hb = (r >> 11) << 11;                  // head-row base in (B*H*S)
    const int mrow = (b << 11) + q;
    const int cnt = counts[mrow];
    const unsigned short* id = idx + ((size_t)mrow << 11);
    const int d = lane & 31, half = lane >> 5;
    const float qv = Q[((size_t)r << 5) + d];
    float* s = sc[wave];
    float acc = 0.f;

    if (cnt > 0) {
        for (int i = 0; i < cnt; i += 2) {
            const int i0 = i + half;
            float p = 0.f;
            if (i0 < cnt) p = qv * K[((size_t)(hb + id[i0]) << 5) + d];
            p += __shfl_xor(p, 1);  p += __shfl_xor(p, 2);  p += __shfl_xor(p, 4);
            p += __shfl_xor(p, 8);  p += __shfl_xor(p, 16);
            if (d == 0 && i0 < cnt) s[i0] = p * 0.17677669529663687f;
        }
        asm volatile("s_waitcnt lgkmcnt(0)" ::: "memory");
        __builtin_amdgcn_sched_barrier(0);
        float mx = -1e30f;
        for (int j = lane; j < cnt; j += 64) mx = fmaxf(mx, s[j]);
        for (int o = 32; o; o >>= 1) mx = fmaxf(mx, __shfl_xor(mx, o));
        float sum = 0.f;
        for (int j = lane; j < cnt; j += 64) {
            const float e = __expf(s[j] - mx);
            s[j] = e;
            sum += e;
        }
        for (int o = 32; o; o >>= 1) sum += __shfl_xor(sum, o);
        asm volatile("s_waitcnt lgkmcnt(0)" ::: "memory");
        __builtin_amdgcn_sched_barrier(0);
        const float inv = 1.f / sum;
        for (int i = 0; i < cnt; i += 2) {
            const int i0 = i + half;
            if (i0 < cnt) acc += s[i0] * V[((size_t)(hb + id[i0]) << 5) + d];
        }
        acc *= inv;
    } else {
        // all-masked row: softmax of uniform -1e9 == uniform weights
        for (int kk = half; kk < SEQ; kk += 2)
            acc += V[((size_t)(hb + kk) << 5) + d];
        acc *= (1.f/SEQ);
    }
    acc += __shfl_xor(acc, 32);
    if (lane < 32) out[((size_t)mrow << 8) + (h << 5) + d] = acc;
}

// ---------------------------------------------------------------------------
extern "C" void kernel_launch(void* const* d_in, const int* in_sizes, int n_in,
                              void* d_out, int out_size, void* d_ws, size_t ws_size,
                              hipStream_t stream)
{
    const float* x    = (const float*)d_in[0];
    const void*  mask = d_in[1];
    const float* ln1g = (const float*)d_in[2];
    const float* ln1b = (const float*)d_in[3];
    const float* ln2g = (const float*)d_in[4];
    const float* ln2b = (const float*)d_in[5];
    const float* Wq   = (const float*)d_in[6];
    const float* bq   = (const float*)d_in[7];
    const float* Wk   = (const float*)d_in[8];
    const float* bk   = (const float*)d_in[9];
    const float* Wv   = (const float*)d_in[10];
    const float* bv   = (const float*)d_in[11];
    const float* Wo   = (const float*)d_in[12];
    const float* bo   = (const float*)d_in[13];
    const float* W1   = (const float*)d_in[14];
    const float* b1   = (const float*)d_in[15];
    const float* W2   = (const float*)d_in[16];
    const float* b2   = (const float*)d_in[17];

    // Workspace map (36 MB total), with audited stream-ordered aliasing:
    //   [0,4)        flag
    //   [1024,17K)   counts
    //   [32K,16M+32K)    idx  (dead after attn)  -> reused as hbuf (16 MB)
    //   +0           nx   (dead after V gemm)    -> reused as attn (4 MB)
    //   +4M          qb   (dead after attn)      -> reused as nx2  (4 MB)
    //   +8M          kb                             (4 MB)
    //   +12M         vbuf                           (4 MB)
    //   +16M         x1                             (4 MB)
    char* w = (char*)d_ws;
    unsigned* flag      = (unsigned*)(w);
    int* counts         = (int*)(w + 1024);
    unsigned short* idx = (unsigned short*)(w + 32768);
    float* hbuf         = (float*)(w + 32768);                    // alias of idx
    float* nx   = (float*)(w + 32768 + ((size_t)16 << 20));
    float* attn = nx;                                             // alias of nx
    float* qb   = nx   + (size_t)MROWS * HID;
    float* nx2  = qb;                                             // alias of qb
    float* kb   = qb   + (size_t)MROWS * HID;
    float* vbuf = kb   + (size_t)MROWS * HID;
    float* x1   = vbuf + (size_t)MROWS * HID;
    float* ob   = (float*)d_out;

    hipMemsetAsync(flag, 0, 4, stream);
    detect_mask<<<1024, 256, 0, stream>>>((const unsigned*)mask, flag);
    build_idx<<<MROWS, 256, 0, stream>>>(mask, flag, counts, idx);
    ln256<<<MROWS, 256, 0, stream>>>(x, ln1g, ln1b, nx);
    gemm16<256,0><<<MROWS/16, 256, 0, stream>>>(nx, Wq, bq, nullptr, qb,   HID);
    gemm16<256,0><<<MROWS/16, 256, 0, stream>>>(nx, Wk, bk, nullptr, kb,   HID);
    gemm16<256,0><<<MROWS/16, 256, 0, stream>>>(nx, Wv, bv, nullptr, vbuf, HID);
    attn_sparse<<<(BATCH*HEADS*SEQ)/4, 256, 0, stream>>>(qb, kb, vbuf, idx, counts, attn);
    gemm16<256,1><<<MROWS/16, 256, 0, stream>>>(attn, Wo, bo, x, x1, HID);
    ln256<<<MROWS, 256, 0, stream>>>(x1, ln2g, ln2b, nx2);
    gemm16<256,2><<<MROWS/16, 256, 0, stream>>>(nx2, W1, b1, nullptr, hbuf, 4*HID);
    gemm16<1024,1><<<MROWS/16, 256, 0, stream>>>(hbuf, W2, b2, x1, ob, HID);
}

// Round 4
// 481.290 us; speedup vs baseline: 2.0965x; 2.0965x over previous
//
#include <hip/hip_runtime.h>
#include <hip/hip_bf16.h>

#define HID 256
#define HEADS 8
#define HDIM 32
#define BATCH 2
#define SEQ 2048
#define MROWS (BATCH*SEQ)   // 4096

// ---------------------------------------------------------------------------
// Mask dtype detection (unchanged, correct): flag!=0 => byte mask.
// ---------------------------------------------------------------------------
__global__ __launch_bounds__(256) void detect_mask(const unsigned* __restrict__ m,
                                                   unsigned* __restrict__ flag)
{
    unsigned bad = 0;
    for (size_t i = (size_t)blockIdx.x * 256 + threadIdx.x; i < 2097152u;
         i += (size_t)gridDim.x * 256) {
        const unsigned wv = m[i];
        if (wv != 0u && wv != 1u && wv != 0x3F800000u) bad = 1;
    }
    if (__ballot(bad)) {
        if ((threadIdx.x & 63) == 0) atomicOr(flag, 1u);
    }
}

// Compact per-(b,q) row adjacency into index lists (order irrelevant).
__global__ __launch_bounds__(256) void build_idx(const void* __restrict__ mask,
                                                 const unsigned* __restrict__ flag,
                                                 int* __restrict__ counts,
                                                 unsigned short* __restrict__ idx)
{
    const int row = blockIdx.x;          // b*SEQ + q
    __shared__ int cnt;
    if (threadIdx.x == 0) cnt = 0;
    __syncthreads();
    const int bytemode = (*flag != 0);
    unsigned short* dst = idx + ((size_t)row << 11);
    for (int k = threadIdx.x; k < SEQ; k += 256) {
        int set;
        if (bytemode) set = ((const unsigned char*)mask)[((size_t)row << 11) + k] != 0;
        else          set = ((const unsigned*)mask)[((size_t)row << 11) + k] != 0u;
        if (set) {
            const int p = atomicAdd(&cnt, 1);
            dst[p] = (unsigned short)k;
        }
    }
    __syncthreads();
    if (threadIdx.x == 0) counts[row] = cnt;
}

// ---------------------------------------------------------------------------
// LayerNorm: one 256-thread block per row of 256.
// ---------------------------------------------------------------------------
__global__ __launch_bounds__(256) void ln256(const float* __restrict__ in,
                                             const float* __restrict__ g,
                                             const float* __restrict__ b,
                                             float* __restrict__ out)
{
    const int row = blockIdx.x, tid = threadIdx.x;
    __shared__ float red[256];
    const float v = in[((size_t)row << 8) + tid];
    red[tid] = v; __syncthreads();
    for (int s = 128; s > 0; s >>= 1) {
        if (tid < s) red[tid] += red[tid + s];
        __syncthreads();
    }
    const float m = red[0] * (1.f/HID);
    __syncthreads();
    const float dv = v - m;
    red[tid] = dv * dv; __syncthreads();
    for (int s = 128; s > 0; s >>= 1) {
        if (tid < s) red[tid] += red[tid + s];
        __syncthreads();
    }
    const float var = red[0] * (1.f/HID);
    out[((size_t)row << 8) + tid] = dv * rsqrtf(var + 1e-5f) * g[tid] + b[tid];
}

// ---------------------------------------------------------------------------
// fp32 GEMM: C[M x N] = A[M x KTOT] @ W[KTOT x N] + bias, epilogue variants.
// Block = 256 threads handles 8 rows; grid.y = N/256 col chunk (occupancy!).
// EPI 0: scatter to (B,H,S,D) layout (QKV).   EPI 1: + res -> out (Wo, W2).
// EPI 2: exact GELU -> out (W1).
// ---------------------------------------------------------------------------
template<int KTOT, int EPI>
__global__ __launch_bounds__(256) void gemm8(const float* __restrict__ A,
                                             const float* __restrict__ W,
                                             const float* __restrict__ bias,
                                             const float* __restrict__ res,
                                             float* __restrict__ out,
                                             int N)
{
    __shared__ float a[8][256];
    const int tid = threadIdx.x;
    const int r0 = blockIdx.x * 8;
    const int c  = blockIdx.y * 256 + tid;
    float acc[8];
#pragma unroll
    for (int r = 0; r < 8; ++r) acc[r] = 0.f;
    for (int kc = 0; kc < KTOT; kc += 256) {
        __syncthreads();
#pragma unroll
        for (int i = tid; i < 8*256; i += 256)
            a[i >> 8][i & 255] = A[(size_t)(r0 + (i >> 8)) * KTOT + kc + (i & 255)];
        __syncthreads();
        for (int k = 0; k < 256; k += 4) {
            const size_t wb = (size_t)(kc + k) * N + c;
            const float w0 = W[wb];
            const float w1 = W[wb + (size_t)N];
            const float w2 = W[wb + 2*(size_t)N];
            const float w3 = W[wb + 3*(size_t)N];
#pragma unroll
            for (int r = 0; r < 8; ++r) {
                const float4 av = *(const float4*)(&a[r][k]);
                acc[r] = fmaf(av.x, w0, acc[r]);
                acc[r] = fmaf(av.y, w1, acc[r]);
                acc[r] = fmaf(av.z, w2, acc[r]);
                acc[r] = fmaf(av.w, w3, acc[r]);
            }
        }
    }
    const float bv = bias[c];
#pragma unroll
    for (int r = 0; r < 8; ++r) {
        const int row = r0 + r;
        const float v = acc[r] + bv;
        if (EPI == 0) {
            const int bb = row >> 11, s = row & 2047, h = c >> 5, d = c & 31;
            out[(((size_t)(bb * HEADS + h) * SEQ + s) << 5) + d] = v;
        } else if (EPI == 1) {
            const size_t o = (size_t)row * N + c;
            out[o] = v + res[o];
        } else {
            const size_t o = (size_t)row * N + c;
            out[o] = 0.5f * v * (1.0f + erff(v * 0.70710678118654752f));
        }
    }
}

// ---------------------------------------------------------------------------
// Sparse masked attention, v2: lane-owns-key structure, NO per-key shuffles.
// One wave per (b,h,q) row; 4 waves/block; tiny LDS (occupancy-friendly).
// Scores are bounded (|s| << 80): softmax without max-subtraction is exact
// (shift invariance), so no max reduce and no online rescale are needed.
// Per 64-key chunk: lane j computes p_j = exp(q.K[id[j]]/sqrt(D)) via
// LDS-broadcast q (float4) x per-lane K float4 loads; p,id staged in LDS;
// then d-parallel coalesced PV accumulate. One 6-shfl sum reduce per ROW.
// ---------------------------------------------------------------------------
__global__ __launch_bounds__(256) void attn_sparse(const float* __restrict__ Q,
                                                   const float* __restrict__ K,
                                                   const float* __restrict__ V,
                                                   const unsigned short* __restrict__ idx,
                                                   const int* __restrict__ counts,
                                                   float* __restrict__ out)
{
    __shared__ float q_s[4][32];
    __shared__ float p_s[4][64];
    __shared__ int  id_s[4][64];
    const int tid  = threadIdx.x;
    const int wave = tid >> 6, lane = tid & 63;
    const int r = blockIdx.x * 4 + wave;             // (b*H + h)*SEQ + q
    const int b = r >> 14, h = (r >> 11) & 7, q = r & 2047;
    const int hb = (r >> 11) << 11;                  // head-row base in (B*H*S)
    const int mrow = (b << 11) + q;
    const int cnt = counts[mrow];
    const unsigned short* id = idx + ((size_t)mrow << 11);
    const int d = lane & 31, half = lane >> 5;
    float acc = 0.f;

    if (cnt > 0) {
        // stage q row (128B) into LDS
        if (lane < 32) q_s[wave][lane] = Q[((size_t)r << 5) + lane];
        asm volatile("s_waitcnt lgkmcnt(0)" ::: "memory");
        __builtin_amdgcn_sched_barrier(0);
        const float4* q4 = (const float4*)q_s[wave];
        float l_lane = 0.f;
        for (int c0 = 0; c0 < cnt; c0 += 64) {
            const int j = c0 + lane;
            const int valid = j < cnt;
            const int ki = valid ? (int)id[j] : 0;
            float p = 0.f;
            if (valid) {
                const float4* Kr = (const float4*)(K + ((size_t)(hb + ki) << 5));
                float s = 0.f;
#pragma unroll
                for (int dd = 0; dd < 8; ++dd) {
                    const float4 kv = Kr[dd];
                    const float4 qv = q4[dd];
                    s = fmaf(kv.x, qv.x, s);
                    s = fmaf(kv.y, qv.y, s);
                    s = fmaf(kv.z, qv.z, s);
                    s = fmaf(kv.w, qv.w, s);
                }
                p = __expf(s * 0.17677669529663687f);
            }
            l_lane += p;
            p_s[wave][lane]  = p;
            id_s[wave][lane] = ki;
            asm volatile("s_waitcnt lgkmcnt(0)" ::: "memory");
            __builtin_amdgcn_sched_barrier(0);
            // d-parallel PV: half 0 takes even j, half 1 odd j (coalesced V rows)
            const int v = (cnt - c0 < 64) ? (cnt - c0) : 64;
            for (int jj = half; jj < v; jj += 2)
                acc = fmaf(p_s[wave][jj],
                           V[((size_t)(hb + id_s[wave][jj]) << 5) + d], acc);
            asm volatile("s_waitcnt lgkmcnt(0)" ::: "memory");
            __builtin_amdgcn_sched_barrier(0);
        }
        // combine halves and normalize
        acc += __shfl_xor(acc, 32);
        float l = l_lane;
        for (int o = 32; o; o >>= 1) l += __shfl_xor(l, o);
        if (lane < 32) out[((size_t)mrow << 8) + (h << 5) + d] = acc / l;
    } else {
        // all-masked row: softmax of uniform -1e9 == uniform weights
        for (int kk = half; kk < SEQ; kk += 2)
            acc += V[((size_t)(hb + kk) << 5) + d];
        acc *= (1.f/SEQ);
        acc += __shfl_xor(acc, 32);
        if (lane < 32) out[((size_t)mrow << 8) + (h << 5) + d] = acc;
    }
}

// ---------------------------------------------------------------------------
extern "C" void kernel_launch(void* const* d_in, const int* in_sizes, int n_in,
                              void* d_out, int out_size, void* d_ws, size_t ws_size,
                              hipStream_t stream)
{
    const float* x    = (const float*)d_in[0];
    const void*  mask = d_in[1];
    const float* ln1g = (const float*)d_in[2];
    const float* ln1b = (const float*)d_in[3];
    const float* ln2g = (const float*)d_in[4];
    const float* ln2b = (const float*)d_in[5];
    const float* Wq   = (const float*)d_in[6];
    const float* bq   = (const float*)d_in[7];
    const float* Wk   = (const float*)d_in[8];
    const float* bk   = (const float*)d_in[9];
    const float* Wv   = (const float*)d_in[10];
    const float* bv   = (const float*)d_in[11];
    const float* Wo   = (const float*)d_in[12];
    const float* bo   = (const float*)d_in[13];
    const float* W1   = (const float*)d_in[14];
    const float* b1   = (const float*)d_in[15];
    const float* W2   = (const float*)d_in[16];
    const float* b2   = (const float*)d_in[17];

    // Workspace map (36 MB), stream-ordered aliasing audited:
    //   idx (dead after attn) -> hbuf ; nx (dead after V gemm) -> attn ;
    //   qb (dead after attn) -> nx2
    char* w = (char*)d_ws;
    unsigned* flag      = (unsigned*)(w);
    int* counts         = (int*)(w + 1024);
    unsigned short* idx = (unsigned short*)(w + 32768);
    float* hbuf         = (float*)(w + 32768);                    // alias of idx
    float* nx   = (float*)(w + 32768 + ((size_t)16 << 20));
    float* attn = nx;                                             // alias of nx
    float* qb   = nx   + (size_t)MROWS * HID;
    float* nx2  = qb;                                             // alias of qb
    float* kb   = qb   + (size_t)MROWS * HID;
    float* vbuf = kb   + (size_t)MROWS * HID;
    float* x1   = vbuf + (size_t)MROWS * HID;
    float* ob   = (float*)d_out;

    hipMemsetAsync(flag, 0, 4, stream);
    detect_mask<<<1024, 256, 0, stream>>>((const unsigned*)mask, flag);
    build_idx<<<MROWS, 256, 0, stream>>>(mask, flag, counts, idx);
    ln256<<<MROWS, 256, 0, stream>>>(x, ln1g, ln1b, nx);
    gemm8<256,0><<<dim3(MROWS/8,1), 256, 0, stream>>>(nx, Wq, bq, nullptr, qb,   HID);
    gemm8<256,0><<<dim3(MROWS/8,1), 256, 0, stream>>>(nx, Wk, bk, nullptr, kb,   HID);
    gemm8<256,0><<<dim3(MROWS/8,1), 256, 0, stream>>>(nx, Wv, bv, nullptr, vbuf, HID);
    attn_sparse<<<(BATCH*HEADS*SEQ)/4, 256, 0, stream>>>(qb, kb, vbuf, idx, counts, attn);
    gemm8<256,1><<<dim3(MROWS/8,1), 256, 0, stream>>>(attn, Wo, bo, x, x1, HID);
    ln256<<<MROWS, 256, 0, stream>>>(x1, ln2g, ln2b, nx2);
    gemm8<256,2><<<dim3(MROWS/8,4), 256, 0, stream>>>(nx2, W1, b1, nullptr, hbuf, 4*HID);
    gemm8<1024,1><<<dim3(MROWS/8,1), 256, 0, stream>>>(hbuf, W2, b2, x1, ob, HID);
}

// Round 5
// 308.369 us; speedup vs baseline: 3.2721x; 1.5608x over previous
//
#include <hip/hip_runtime.h>
#include <hip/hip_bf16.h>

#define HID 256
#define HEADS 8
#define HDIM 32
#define BATCH 2
#define SEQ 2048
#define MROWS (BATCH*SEQ)   // 4096

typedef __attribute__((ext_vector_type(8))) short short8;   // 8 bf16 (4 VGPRs)
typedef __attribute__((ext_vector_type(4))) float f32x4;

// ---------------------------------------------------------------------------
// Mask dtype detection: flag!=0 => byte mask.
// ---------------------------------------------------------------------------
__global__ __launch_bounds__(256) void detect_mask(const unsigned* __restrict__ m,
                                                   unsigned* __restrict__ flag)
{
    unsigned bad = 0;
    for (size_t i = (size_t)blockIdx.x * 256 + threadIdx.x; i < 2097152u;
         i += (size_t)gridDim.x * 256) {
        const unsigned wv = m[i];
        if (wv != 0u && wv != 1u && wv != 0x3F800000u) bad = 1;
    }
    if (__ballot(bad)) {
        if ((threadIdx.x & 63) == 0) atomicOr(flag, 1u);
    }
}

// ---------------------------------------------------------------------------
// Row adjacency -> index lists via wave ballot compaction (8 atomics/wave).
// ---------------------------------------------------------------------------
__global__ __launch_bounds__(256) void build_idx(const void* __restrict__ mask,
                                                 const unsigned* __restrict__ flag,
                                                 int* __restrict__ counts,
                                                 unsigned short* __restrict__ idx)
{
    const int row = blockIdx.x;          // b*SEQ + q
    __shared__ int cnt;
    if (threadIdx.x == 0) cnt = 0;
    __syncthreads();
    const int bytemode = (*flag != 0);
    const int wave = threadIdx.x >> 6, lane = threadIdx.x & 63;
    unsigned short* dst = idx + ((size_t)row << 11);
    for (int k0 = wave * 64; k0 < SEQ; k0 += 256) {
        const int k = k0 + lane;
        int set;
        if (bytemode) set = ((const unsigned char*)mask)[((size_t)row << 11) + k] != 0;
        else          set = ((const unsigned*)mask)[((size_t)row << 11) + k] != 0u;
        const unsigned long long bal = __ballot(set);
        const int tot = __popcll(bal);
        int base = 0;
        if (lane == 0 && tot) base = atomicAdd(&cnt, tot);
        base = __shfl(base, 0);
        if (set)
            dst[base + __popcll(bal & ((1ull << lane) - 1ull))] = (unsigned short)k;
    }
    __syncthreads();
    if (threadIdx.x == 0) counts[row] = cnt;
}

// ---------------------------------------------------------------------------
// Transpose-convert weights: W[K][N] fp32 -> Wt[N][K] bf16 (32x32 LDS tiles).
// ---------------------------------------------------------------------------
__global__ __launch_bounds__(256) void tconv(const float* __restrict__ W,
                                             __hip_bfloat16* __restrict__ Wt,
                                             int K, int N)
{
    __shared__ float t[32][33];
    const int tx = threadIdx.x & 31, ty = threadIdx.x >> 5;
    const int n0 = blockIdx.x * 32, k0 = blockIdx.y * 32;
#pragma unroll
    for (int i = 0; i < 4; ++i)
        t[ty + i*8][tx] = W[(size_t)(k0 + ty + i*8) * N + n0 + tx];
    __syncthreads();
#pragma unroll
    for (int i = 0; i < 4; ++i)
        Wt[(size_t)(n0 + ty + i*8) * K + k0 + tx] = __float2bfloat16(t[tx][ty + i*8]);
}

// ---------------------------------------------------------------------------
// LayerNorm: one 256-thread block per row of 256; bf16 output (GEMM A-side).
// ---------------------------------------------------------------------------
__global__ __launch_bounds__(256) void ln256(const float* __restrict__ in,
                                             const float* __restrict__ g,
                                             const float* __restrict__ b,
                                             __hip_bfloat16* __restrict__ out)
{
    const int row = blockIdx.x, tid = threadIdx.x;
    __shared__ float red[256];
    const float v = in[((size_t)row << 8) + tid];
    red[tid] = v; __syncthreads();
    for (int s = 128; s > 0; s >>= 1) {
        if (tid < s) red[tid] += red[tid + s];
        __syncthreads();
    }
    const float m = red[0] * (1.f/HID);
    __syncthreads();
    const float dv = v - m;
    red[tid] = dv * dv; __syncthreads();
    for (int s = 128; s > 0; s >>= 1) {
        if (tid < s) red[tid] += red[tid + s];
        __syncthreads();
    }
    const float var = red[0] * (1.f/HID);
    out[((size_t)row << 8) + tid] =
        __float2bfloat16(dv * rsqrtf(var + 1e-5f) * g[tid] + b[tid]);
}

// ---------------------------------------------------------------------------
// bf16 MFMA GEMM: C[M x N] = A[M x KTOT] @ W + bias.  A row-major bf16,
// weights pre-transposed bf16 Wt[N][KTOT] so B-fragments are contiguous.
// Block 256 = 4 waves, tile 64x64, wave tile 32x32 (2x2 16x16 frags).
// No LDS: A (2MB) and Wt (<=0.5MB) are L2-resident; frag = 16B/lane load.
// Frag layouts (16x16x32): A lane l elem j -> A[l&15][(l>>4)*8+j];
// B lane l elem j -> B[(l>>4)*8+j][l&15] = Wt[l&15][(l>>4)*8+j];
// D lane l reg r -> row=(l>>4)*4+r, col=l&15  (m89-verified).
// EPI 0: scatter fp32 to (B,H,S,D).  EPI 1: +res fp32.  EPI 2: GELU -> bf16.
// ---------------------------------------------------------------------------
template<int KTOT, int EPI>
__global__ __launch_bounds__(256) void gemm_mfma(const __hip_bfloat16* __restrict__ A,
                                                 const __hip_bfloat16* __restrict__ Wt,
                                                 const float* __restrict__ bias,
                                                 const float* __restrict__ res,
                                                 float* __restrict__ outF,
                                                 __hip_bfloat16* __restrict__ outB,
                                                 int N)
{
    const int tid = threadIdx.x;
    const int wv = tid >> 6, lane = tid & 63;
    const int wr = wv >> 1, wc = wv & 1;
    const int r0 = blockIdx.x * 64 + wr * 32;
    const int c0 = blockIdx.y * 64 + wc * 32;
    const int al = lane & 15, ah = lane >> 4;

    f32x4 acc[2][2] = {};
    const short8* Ap[2];
    const short8* Bp[2];
#pragma unroll
    for (int m = 0; m < 2; ++m)
        Ap[m] = (const short8*)(A + (size_t)(r0 + m*16 + al) * KTOT + ah * 8);
#pragma unroll
    for (int n = 0; n < 2; ++n)
        Bp[n] = (const short8*)(Wt + (size_t)(c0 + n*16 + al) * KTOT + ah * 8);

#pragma unroll 8
    for (int kt = 0; kt < KTOT/32; ++kt) {
        short8 af[2], bf[2];
#pragma unroll
        for (int m = 0; m < 2; ++m) af[m] = Ap[m][kt*4];
#pragma unroll
        for (int n = 0; n < 2; ++n) bf[n] = Bp[n][kt*4];
#pragma unroll
        for (int m = 0; m < 2; ++m)
#pragma unroll
            for (int n = 0; n < 2; ++n)
                acc[m][n] = __builtin_amdgcn_mfma_f32_16x16x32_bf16(
                    af[m], bf[n], acc[m][n], 0, 0, 0);
    }

#pragma unroll
    for (int m = 0; m < 2; ++m)
#pragma unroll
        for (int n = 0; n < 2; ++n) {
            const int col = c0 + n*16 + al;
            const float bv = bias[col];
#pragma unroll
            for (int r = 0; r < 4; ++r) {
                const int row = r0 + m*16 + ah*4 + r;
                const float v = acc[m][n][r] + bv;
                if (EPI == 0) {
                    const int bb = row >> 11, s = row & 2047, h = col >> 5, d = col & 31;
                    outF[(((size_t)(bb * HEADS + h) * SEQ + s) << 5) + d] = v;
                } else if (EPI == 1) {
                    const size_t o = (size_t)row * N + col;
                    outF[o] = v + res[o];
                } else {
                    const size_t o = (size_t)row * N + col;
                    outB[o] = __float2bfloat16(
                        0.5f * v * (1.0f + erff(v * 0.70710678118654752f)));
                }
            }
        }
}

// ---------------------------------------------------------------------------
// Sparse masked attention (round-4 structure, bf16 output for Wo's A-side).
// ---------------------------------------------------------------------------
__global__ __launch_bounds__(256) void attn_sparse(const float* __restrict__ Q,
                                                   const float* __restrict__ K,
                                                   const float* __restrict__ V,
                                                   const unsigned short* __restrict__ idx,
                                                   const int* __restrict__ counts,
                                                   __hip_bfloat16* __restrict__ out)
{
    __shared__ float q_s[4][32];
    __shared__ float p_s[4][64];
    __shared__ int  id_s[4][64];
    const int tid  = threadIdx.x;
    const int wave = tid >> 6, lane = tid & 63;
    const int r = blockIdx.x * 4 + wave;             // (b*H + h)*SEQ + q
    const int b = r >> 14, h = (r >> 11) & 7, q = r & 2047;
    const int hb = (r >> 11) << 11;                  // head-row base in (B*H*S)
    const int mrow = (b << 11) + q;
    const int cnt = counts[mrow];
    const unsigned short* id = idx + ((size_t)mrow << 11);
    const int d = lane & 31, half = lane >> 5;
    float acc = 0.f;

    if (cnt > 0) {
        if (lane < 32) q_s[wave][lane] = Q[((size_t)r << 5) + lane];
        asm volatile("s_waitcnt lgkmcnt(0)" ::: "memory");
        __builtin_amdgcn_sched_barrier(0);
        const float4* q4 = (const float4*)q_s[wave];
        float l_lane = 0.f;
        for (int c0 = 0; c0 < cnt; c0 += 64) {
            const int j = c0 + lane;
            const int valid = j < cnt;
            const int ki = valid ? (int)id[j] : 0;
            float p = 0.f;
            if (valid) {
                const float4* Kr = (const float4*)(K + ((size_t)(hb + ki) << 5));
                float s = 0.f;
#pragma unroll
                for (int dd = 0; dd < 8; ++dd) {
                    const float4 kv = Kr[dd];
                    const float4 qv = q4[dd];
                    s = fmaf(kv.x, qv.x, s);
                    s = fmaf(kv.y, qv.y, s);
                    s = fmaf(kv.z, qv.z, s);
                    s = fmaf(kv.w, qv.w, s);
                }
                p = __expf(s * 0.17677669529663687f);
            }
            l_lane += p;
            p_s[wave][lane]  = p;
            id_s[wave][lane] = ki;
            asm volatile("s_waitcnt lgkmcnt(0)" ::: "memory");
            __builtin_amdgcn_sched_barrier(0);
            const int v = (cnt - c0 < 64) ? (cnt - c0) : 64;
            for (int jj = half; jj < v; jj += 2)
                acc = fmaf(p_s[wave][jj],
                           V[((size_t)(hb + id_s[wave][jj]) << 5) + d], acc);
            asm volatile("s_waitcnt lgkmcnt(0)" ::: "memory");
            __builtin_amdgcn_sched_barrier(0);
        }
        acc += __shfl_xor(acc, 32);
        float l = l_lane;
        for (int o = 32; o; o >>= 1) l += __shfl_xor(l, o);
        if (lane < 32)
            out[((size_t)mrow << 8) + (h << 5) + d] = __float2bfloat16(acc / l);
    } else {
        for (int kk = half; kk < SEQ; kk += 2)
            acc += V[((size_t)(hb + kk) << 5) + d];
        acc *= (1.f/SEQ);
        acc += __shfl_xor(acc, 32);
        if (lane < 32)
            out[((size_t)mrow << 8) + (h << 5) + d] = __float2bfloat16(acc);
    }
}

// ---------------------------------------------------------------------------
extern "C" void kernel_launch(void* const* d_in, const int* in_sizes, int n_in,
                              void* d_out, int out_size, void* d_ws, size_t ws_size,
                              hipStream_t stream)
{
    const float* x    = (const float*)d_in[0];
    const void*  mask = d_in[1];
    const float* ln1g = (const float*)d_in[2];
    const float* ln1b = (const float*)d_in[3];
    const float* ln2g = (const float*)d_in[4];
    const float* ln2b = (const float*)d_in[5];
    const float* Wq   = (const float*)d_in[6];
    const float* bq   = (const float*)d_in[7];
    const float* Wk   = (const float*)d_in[8];
    const float* bk   = (const float*)d_in[9];
    const float* Wv   = (const float*)d_in[10];
    const float* bv   = (const float*)d_in[11];
    const float* Wo   = (const float*)d_in[12];
    const float* bo   = (const float*)d_in[13];
    const float* W1   = (const float*)d_in[14];
    const float* b1   = (const float*)d_in[15];
    const float* W2   = (const float*)d_in[16];
    const float* b2   = (const float*)d_in[17];

    // Workspace map (~35.6 MB), stream-ordered aliasing audited:
    //   idx (dead after attn) -> hbuf ; nx (dead after V gemm) -> attn_b ;
    //   qb (dead after attn) -> nx2
    char* w = (char*)d_ws;
    unsigned* flag      = (unsigned*)(w);
    int* counts         = (int*)(w + 1024);
    unsigned short* idx = (unsigned short*)(w + 32768);
    __hip_bfloat16* hbuf = (__hip_bfloat16*)(w + 32768);          // alias of idx
    char* base = w + 32768 + ((size_t)16 << 20);
    __hip_bfloat16* nx     = (__hip_bfloat16*)(base);             // 2 MB
    __hip_bfloat16* attn_b = nx;                                  // alias of nx
    float* qb   = (float*)(base + ((size_t)2 << 20));             // 4 MB
    __hip_bfloat16* nx2 = (__hip_bfloat16*)qb;                    // alias of qb
    float* kb   = qb + (size_t)MROWS * HID;                       // 4 MB
    float* vbuf = kb + (size_t)MROWS * HID;                       // 4 MB
    float* x1   = vbuf + (size_t)MROWS * HID;                     // 4 MB
    __hip_bfloat16* wts = (__hip_bfloat16*)(x1 + (size_t)MROWS * HID);
    __hip_bfloat16* Wtq = wts;                                    // 256x256 each
    __hip_bfloat16* Wtk = Wtq + 65536;
    __hip_bfloat16* Wtv = Wtk + 65536;
    __hip_bfloat16* Wto = Wtv + 65536;
    __hip_bfloat16* Wt1 = Wto + 65536;                            // [1024][256]
    __hip_bfloat16* Wt2 = Wt1 + 262144;                           // [256][1024]
    float* ob   = (float*)d_out;

    hipMemsetAsync(flag, 0, 4, stream);
    detect_mask<<<1024, 256, 0, stream>>>((const unsigned*)mask, flag);
    build_idx<<<MROWS, 256, 0, stream>>>(mask, flag, counts, idx);
    tconv<<<dim3(8,8),   256, 0, stream>>>(Wq, Wtq, 256, 256);
    tconv<<<dim3(8,8),   256, 0, stream>>>(Wk, Wtk, 256, 256);
    tconv<<<dim3(8,8),   256, 0, stream>>>(Wv, Wtv, 256, 256);
    tconv<<<dim3(8,8),   256, 0, stream>>>(Wo, Wto, 256, 256);
    tconv<<<dim3(32,8),  256, 0, stream>>>(W1, Wt1, 256, 1024);
    tconv<<<dim3(8,32),  256, 0, stream>>>(W2, Wt2, 1024, 256);
    ln256<<<MROWS, 256, 0, stream>>>(x, ln1g, ln1b, nx);
    gemm_mfma<256,0><<<dim3(64,4), 256, 0, stream>>>(nx, Wtq, bq, nullptr, qb,   nullptr, HID);
    gemm_mfma<256,0><<<dim3(64,4), 256, 0, stream>>>(nx, Wtk, bk, nullptr, kb,   nullptr, HID);
    gemm_mfma<256,0><<<dim3(64,4), 256, 0, stream>>>(nx, Wtv, bv, nullptr, vbuf, nullptr, HID);
    attn_sparse<<<(BATCH*HEADS*SEQ)/4, 256, 0, stream>>>(qb, kb, vbuf, idx, counts, attn_b);
    gemm_mfma<256,1><<<dim3(64,4), 256, 0, stream>>>(attn_b, Wto, bo, x, x1, nullptr, HID);
    ln256<<<MROWS, 256, 0, stream>>>(x1, ln2g, ln2b, nx2);
    gemm_mfma<256,2><<<dim3(64,16), 256, 0, stream>>>(nx2, Wt1, b1, nullptr, nullptr, hbuf, 4*HID);
    gemm_mfma<1024,1><<<dim3(64,4), 256, 0, stream>>>(hbuf, Wt2, b2, x1, ob, nullptr, HID);
}

// Round 6
// 269.756 us; speedup vs baseline: 3.7404x; 1.1431x over previous
//
#include <hip/hip_runtime.h>
#include <hip/hip_bf16.h>

#define HID 256
#define HEADS 8
#define HDIM 32
#define BATCH 2
#define SEQ 2048
#define MROWS (BATCH*SEQ)   // 4096

typedef __attribute__((ext_vector_type(8))) short short8;   // 8 bf16 (4 VGPRs)
typedef __attribute__((ext_vector_type(4))) float f32x4;

static __device__ __forceinline__ unsigned short f2bf(float x) {
    __hip_bfloat16 h = __float2bfloat16(x);
    return __builtin_bit_cast(unsigned short, h);
}

// ---------------------------------------------------------------------------
// Mask dtype detection: flag!=0 => byte mask.
// ---------------------------------------------------------------------------
__global__ __launch_bounds__(256) void detect_mask(const unsigned* __restrict__ m,
                                                   unsigned* __restrict__ flag)
{
    unsigned bad = 0;
    for (size_t i = (size_t)blockIdx.x * 256 + threadIdx.x; i < 2097152u;
         i += (size_t)gridDim.x * 256) {
        const unsigned wv = m[i];
        if (wv != 0u && wv != 1u && wv != 0x3F800000u) bad = 1;
    }
    if (__ballot(bad)) {
        if ((threadIdx.x & 63) == 0) atomicOr(flag, 1u);
    }
}

// ---------------------------------------------------------------------------
// Row adjacency -> index lists via wave ballot compaction (8 atomics/wave).
// ---------------------------------------------------------------------------
__global__ __launch_bounds__(256) void build_idx(const void* __restrict__ mask,
                                                 const unsigned* __restrict__ flag,
                                                 int* __restrict__ counts,
                                                 unsigned short* __restrict__ idx)
{
    const int row = blockIdx.x;          // b*SEQ + q
    __shared__ int cnt;
    if (threadIdx.x == 0) cnt = 0;
    __syncthreads();
    const int bytemode = (*flag != 0);
    const int wave = threadIdx.x >> 6, lane = threadIdx.x & 63;
    unsigned short* dst = idx + ((size_t)row << 11);
    for (int k0 = wave * 64; k0 < SEQ; k0 += 256) {
        const int k = k0 + lane;
        int set;
        if (bytemode) set = ((const unsigned char*)mask)[((size_t)row << 11) + k] != 0;
        else          set = ((const unsigned*)mask)[((size_t)row << 11) + k] != 0u;
        const unsigned long long bal = __ballot(set);
        const int tot = __popcll(bal);
        int base = 0;
        if (lane == 0 && tot) base = atomicAdd(&cnt, tot);
        base = __shfl(base, 0);
        if (set)
            dst[base + __popcll(bal & ((1ull << lane) - 1ull))] = (unsigned short)k;
    }
    __syncthreads();
    if (threadIdx.x == 0) counts[row] = cnt;
}

// ---------------------------------------------------------------------------
// All weight transposes in ONE launch: W[K][N] fp32 -> Wt[N][K] bf16.
// 768 blocks: [0,64)Wq [64,128)Wk [128,192)Wv [192,256)Wo [256,512)W1 [512,768)W2
// Wq/Wk/Wv land contiguously in Wtqkv => a single [768][256] B for fused QKV.
// ---------------------------------------------------------------------------
__global__ __launch_bounds__(256) void tconv_all(
    const float* __restrict__ Wq, const float* __restrict__ Wk,
    const float* __restrict__ Wv, const float* __restrict__ Wo,
    const float* __restrict__ W1, const float* __restrict__ W2,
    __hip_bfloat16* __restrict__ Wtqkv, __hip_bfloat16* __restrict__ Wto,
    __hip_bfloat16* __restrict__ Wt1,   __hip_bfloat16* __restrict__ Wt2)
{
    const int t = blockIdx.x;
    const float* W; __hip_bfloat16* Wt; int K, N, tt;
    if      (t < 64)  { W = Wq; Wt = Wtqkv;          K = 256;  N = 256;  tt = t; }
    else if (t < 128) { W = Wk; Wt = Wtqkv + 65536;  K = 256;  N = 256;  tt = t - 64; }
    else if (t < 192) { W = Wv; Wt = Wtqkv + 131072; K = 256;  N = 256;  tt = t - 128; }
    else if (t < 256) { W = Wo; Wt = Wto;            K = 256;  N = 256;  tt = t - 192; }
    else if (t < 512) { W = W1; Wt = Wt1;            K = 256;  N = 1024; tt = t - 256; }
    else              { W = W2; Wt = Wt2;            K = 1024; N = 256;  tt = t - 512; }
    const int nt = N >> 5;
    const int n0 = (tt % nt) * 32, k0 = (tt / nt) * 32;
    __shared__ float tle[32][33];
    const int tx = threadIdx.x & 31, ty = threadIdx.x >> 5;
#pragma unroll
    for (int i = 0; i < 4; ++i)
        tle[ty + i*8][tx] = W[(size_t)(k0 + ty + i*8) * N + n0 + tx];
    __syncthreads();
#pragma unroll
    for (int i = 0; i < 4; ++i)
        Wt[(size_t)(n0 + ty + i*8) * K + k0 + tx] = __float2bfloat16(tle[tx][ty + i*8]);
}

// ---------------------------------------------------------------------------
// LayerNorm, wave-per-row (no barriers): 4 rows/block, float4 loads,
// shfl_xor reductions, packed ushort4 bf16 store.
// ---------------------------------------------------------------------------
__global__ __launch_bounds__(256) void ln_wave(const float* __restrict__ in,
                                               const float* __restrict__ g,
                                               const float* __restrict__ b,
                                               __hip_bfloat16* __restrict__ out)
{
    const int wave = threadIdx.x >> 6, lane = threadIdx.x & 63;
    const int row = blockIdx.x * 4 + wave;
    const float4 v = ((const float4*)(in + ((size_t)row << 8)))[lane];
    float s = v.x + v.y + v.z + v.w;
    for (int o = 32; o; o >>= 1) s += __shfl_xor(s, o);
    const float m = s * (1.f/HID);
    const float4 dv = make_float4(v.x - m, v.y - m, v.z - m, v.w - m);
    float vs = dv.x*dv.x + dv.y*dv.y + dv.z*dv.z + dv.w*dv.w;
    for (int o = 32; o; o >>= 1) vs += __shfl_xor(vs, o);
    const float rstd = rsqrtf(vs * (1.f/HID) + 1e-5f);
    const float4 gv = ((const float4*)g)[lane];
    const float4 bv = ((const float4*)b)[lane];
    ushort4 o4;
    o4.x = f2bf(dv.x * rstd * gv.x + bv.x);
    o4.y = f2bf(dv.y * rstd * gv.y + bv.y);
    o4.z = f2bf(dv.z * rstd * gv.z + bv.z);
    o4.w = f2bf(dv.w * rstd * gv.w + bv.w);
    ((ushort4*)(out + ((size_t)row << 8)))[lane] = o4;
}

// ---------------------------------------------------------------------------
// Fused QKV MFMA GEMM: [4096x256] @ Wtqkv[768][256] -> q/k/v in (B,H,S,D).
// Block 256 = 4 waves, tile 64x64, wave 32x32 (2x2 16x16x32 frags), no LDS.
// ---------------------------------------------------------------------------
__global__ __launch_bounds__(256) void gemm_qkv(const __hip_bfloat16* __restrict__ A,
                                                const __hip_bfloat16* __restrict__ Wt,
                                                const float* __restrict__ bq,
                                                const float* __restrict__ bk,
                                                const float* __restrict__ bv,
                                                float* __restrict__ qb,
                                                float* __restrict__ kb,
                                                float* __restrict__ vb)
{
    const int tid = threadIdx.x;
    const int wv = tid >> 6, lane = tid & 63;
    const int wr = wv >> 1, wc = wv & 1;
    const int r0 = blockIdx.x * 64 + wr * 32;
    const int c0 = blockIdx.y * 64 + wc * 32;
    const int al = lane & 15, ah = lane >> 4;

    f32x4 acc[2][2] = {};
    const short8* Ap[2];
    const short8* Bp[2];
#pragma unroll
    for (int m = 0; m < 2; ++m)
        Ap[m] = (const short8*)(A + (size_t)(r0 + m*16 + al) * 256 + ah * 8);
#pragma unroll
    for (int n = 0; n < 2; ++n)
        Bp[n] = (const short8*)(Wt + (size_t)(c0 + n*16 + al) * 256 + ah * 8);

#pragma unroll 8
    for (int kt = 0; kt < 8; ++kt) {
        short8 af[2], bf[2];
#pragma unroll
        for (int m = 0; m < 2; ++m) af[m] = Ap[m][kt*4];
#pragma unroll
        for (int n = 0; n < 2; ++n) bf[n] = Bp[n][kt*4];
#pragma unroll
        for (int m = 0; m < 2; ++m)
#pragma unroll
            for (int n = 0; n < 2; ++n)
                acc[m][n] = __builtin_amdgcn_mfma_f32_16x16x32_bf16(
                    af[m], bf[n], acc[m][n], 0, 0, 0);
    }

#pragma unroll
    for (int m = 0; m < 2; ++m)
#pragma unroll
        for (int n = 0; n < 2; ++n) {
            const int col = c0 + n*16 + al;
            const int which = col >> 8, cc = col & 255;
            const float* bp = which == 0 ? bq : (which == 1 ? bk : bv);
            float* op = which == 0 ? qb : (which == 1 ? kb : vb);
            const float bvv = bp[cc];
#pragma unroll
            for (int r = 0; r < 4; ++r) {
                const int row = r0 + m*16 + ah*4 + r;
                const int bb = row >> 11, s = row & 2047, h = cc >> 5, d = cc & 31;
                op[(((size_t)(bb * HEADS + h) * SEQ + s) << 5) + d] = acc[m][n][r] + bvv;
            }
        }
}

// ---------------------------------------------------------------------------
// bf16 MFMA GEMM (Wo/W1/W2): EPI 1: +res -> fp32.  EPI 2: GELU -> bf16.
// ---------------------------------------------------------------------------
template<int KTOT, int EPI>
__global__ __launch_bounds__(256) void gemm_mfma(const __hip_bfloat16* __restrict__ A,
                                                 const __hip_bfloat16* __restrict__ Wt,
                                                 const float* __restrict__ bias,
                                                 const float* __restrict__ res,
                                                 float* __restrict__ outF,
                                                 __hip_bfloat16* __restrict__ outB,
                                                 int N)
{
    const int tid = threadIdx.x;
    const int wv = tid >> 6, lane = tid & 63;
    const int wr = wv >> 1, wc = wv & 1;
    const int r0 = blockIdx.x * 64 + wr * 32;
    const int c0 = blockIdx.y * 64 + wc * 32;
    const int al = lane & 15, ah = lane >> 4;

    f32x4 acc[2][2] = {};
    const short8* Ap[2];
    const short8* Bp[2];
#pragma unroll
    for (int m = 0; m < 2; ++m)
        Ap[m] = (const short8*)(A + (size_t)(r0 + m*16 + al) * KTOT + ah * 8);
#pragma unroll
    for (int n = 0; n < 2; ++n)
        Bp[n] = (const short8*)(Wt + (size_t)(c0 + n*16 + al) * KTOT + ah * 8);

#pragma unroll 8
    for (int kt = 0; kt < KTOT/32; ++kt) {
        short8 af[2], bf[2];
#pragma unroll
        for (int m = 0; m < 2; ++m) af[m] = Ap[m][kt*4];
#pragma unroll
        for (int n = 0; n < 2; ++n) bf[n] = Bp[n][kt*4];
#pragma unroll
        for (int m = 0; m < 2; ++m)
#pragma unroll
            for (int n = 0; n < 2; ++n)
                acc[m][n] = __builtin_amdgcn_mfma_f32_16x16x32_bf16(
                    af[m], bf[n], acc[m][n], 0, 0, 0);
    }

#pragma unroll
    for (int m = 0; m < 2; ++m)
#pragma unroll
        for (int n = 0; n < 2; ++n) {
            const int col = c0 + n*16 + al;
            const float bv = bias[col];
#pragma unroll
            for (int r = 0; r < 4; ++r) {
                const int row = r0 + m*16 + ah*4 + r;
                const float v = acc[m][n][r] + bv;
                const size_t o = (size_t)row * N + col;
                if (EPI == 1) {
                    outF[o] = v + res[o];
                } else {
                    outB[o] = __float2bfloat16(
                        0.5f * v * (1.0f + erff(v * 0.70710678118654752f)));
                }
            }
        }
}

// ---------------------------------------------------------------------------
// Sparse masked attention v3: lane-owns-key, 4-chain ILP in QK and PV,
// (p,id) packed float2 in LDS, PV reads ds_read_b128 (4 keys per 2 reads).
// Halves take contiguous 32-key ranges of each 64-key chunk.
// Softmax without max-subtraction is exact here (|scores| bounded << 80).
// ---------------------------------------------------------------------------
__global__ __launch_bounds__(256) void attn_sparse(const float* __restrict__ Q,
                                                   const float* __restrict__ K,
                                                   const float* __restrict__ V,
                                                   const unsigned short* __restrict__ idx,
                                                   const int* __restrict__ counts,
                                                   __hip_bfloat16* __restrict__ out)
{
    __shared__ float  q_s[4][32];
    __shared__ float2 pid_s[4][64];
    const int tid  = threadIdx.x;
    const int wave = tid >> 6, lane = tid & 63;
    const int r = blockIdx.x * 4 + wave;             // (b*H + h)*SEQ + q
    const int b = r >> 14, h = (r >> 11) & 7, q = r & 2047;
    const int hb = (r >> 11) << 11;                  // head-row base in (B*H*S)
    const int mrow = (b << 11) + q;
    const int cnt = counts[mrow];
    const unsigned short* id = idx + ((size_t)mrow << 11);
    const int d = lane & 31, half = lane >> 5;
    float a0 = 0.f, a1 = 0.f, a2 = 0.f, a3 = 0.f;

    if (cnt > 0) {
        if (lane < 32) q_s[wave][lane] = Q[((size_t)r << 5) + lane];
        asm volatile("s_waitcnt lgkmcnt(0)" ::: "memory");
        __builtin_amdgcn_sched_barrier(0);
        const float4* q4 = (const float4*)q_s[wave];
        float4 qv[8];
#pragma unroll
        for (int i = 0; i < 8; ++i) qv[i] = q4[i];
        float l_lane = 0.f;

        for (int c0 = 0; c0 < cnt; c0 += 64) {
            const int j = c0 + lane;
            const int valid = j < cnt;
            const int ki = valid ? (int)id[j] : 0;
            float p = 0.f;
            if (valid) {
                const float4* Kr = (const float4*)(K + ((size_t)(hb + ki) << 5));
                const float4 k0 = Kr[0], k1 = Kr[1], k2 = Kr[2], k3 = Kr[3];
                const float4 k4 = Kr[4], k5 = Kr[5], k6 = Kr[6], k7 = Kr[7];
                float s0, s1, s2, s3;
                s0 = k0.x*qv[0].x; s0 = fmaf(k0.y, qv[0].y, s0);
                s0 = fmaf(k0.z, qv[0].z, s0); s0 = fmaf(k0.w, qv[0].w, s0);
                s1 = k1.x*qv[1].x; s1 = fmaf(k1.y, qv[1].y, s1);
                s1 = fmaf(k1.z, qv[1].z, s1); s1 = fmaf(k1.w, qv[1].w, s1);
                s2 = k2.x*qv[2].x; s2 = fmaf(k2.y, qv[2].y, s2);
                s2 = fmaf(k2.z, qv[2].z, s2); s2 = fmaf(k2.w, qv[2].w, s2);
                s3 = k3.x*qv[3].x; s3 = fmaf(k3.y, qv[3].y, s3);
                s3 = fmaf(k3.z, qv[3].z, s3); s3 = fmaf(k3.w, qv[3].w, s3);
                s0 = fmaf(k4.x, qv[4].x, s0); s0 = fmaf(k4.y, qv[4].y, s0);
                s0 = fmaf(k4.z, qv[4].z, s0); s0 = fmaf(k4.w, qv[4].w, s0);
                s1 = fmaf(k5.x, qv[5].x, s1); s1 = fmaf(k5.y, qv[5].y, s1);
                s1 = fmaf(k5.z, qv[5].z, s1); s1 = fmaf(k5.w, qv[5].w, s1);
                s2 = fmaf(k6.x, qv[6].x, s2); s2 = fmaf(k6.y, qv[6].y, s2);
                s2 = fmaf(k6.z, qv[6].z, s2); s2 = fmaf(k6.w, qv[6].w, s2);
                s3 = fmaf(k7.x, qv[7].x, s3); s3 = fmaf(k7.y, qv[7].y, s3);
                s3 = fmaf(k7.z, qv[7].z, s3); s3 = fmaf(k7.w, qv[7].w, s3);
                p = __expf(((s0 + s1) + (s2 + s3)) * 0.17677669529663687f);
            }
            l_lane += p;
            pid_s[wave][lane] = make_float2(p, __int_as_float(ki));
            asm volatile("s_waitcnt lgkmcnt(0)" ::: "memory");
            __builtin_amdgcn_sched_barrier(0);

            const int v  = (cnt - c0 < 64) ? (cnt - c0) : 64;
            const int jb = half * 32;
            const int je = (v - jb < 32) ? (v - jb) : 32;   // keys for this half
            const float4* pp = (const float4*)&pid_s[wave][jb];
            int jj = 0;
            for (; jj + 8 <= je; jj += 8) {
                const float4 P0 = pp[(jj >> 1) + 0], P1 = pp[(jj >> 1) + 1];
                const float4 P2 = pp[(jj >> 1) + 2], P3 = pp[(jj >> 1) + 3];
                a0 = fmaf(P0.x, V[((size_t)(hb + __float_as_int(P0.y)) << 5) + d], a0);
                a1 = fmaf(P0.z, V[((size_t)(hb + __float_as_int(P0.w)) << 5) + d], a1);
                a2 = fmaf(P1.x, V[((size_t)(hb + __float_as_int(P1.y)) << 5) + d], a2);
                a3 = fmaf(P1.z, V[((size_t)(hb + __float_as_int(P1.w)) << 5) + d], a3);
                a0 = fmaf(P2.x, V[((size_t)(hb + __float_as_int(P2.y)) << 5) + d], a0);
                a1 = fmaf(P2.z, V[((size_t)(hb + __float_as_int(P2.w)) << 5) + d], a1);
                a2 = fmaf(P3.x, V[((size_t)(hb + __float_as_int(P3.y)) << 5) + d], a2);
                a3 = fmaf(P3.z, V[((size_t)(hb + __float_as_int(P3.w)) << 5) + d], a3);
            }
            for (; jj < je; ++jj) {
                const float2 pr = pid_s[wave][jb + jj];
                a0 = fmaf(pr.x, V[((size_t)(hb + __float_as_int(pr.y)) << 5) + d], a0);
            }
            asm volatile("s_waitcnt lgkmcnt(0)" ::: "memory");
            __builtin_amdgcn_sched_barrier(0);
        }
        float acc = (a0 + a1) + (a2 + a3);
        acc += __shfl_xor(acc, 32);
        float l = l_lane;
        for (int o = 32; o; o >>= 1) l += __shfl_xor(l, o);
        if (lane < 32)
            out[((size_t)mrow << 8) + (h << 5) + d] = __float2bfloat16(acc / l);
    } else {
        // all-masked row: softmax of uniform -1e9 == uniform weights
        for (int kk = half; kk < SEQ; kk += 2)
            a0 += V[((size_t)(hb + kk) << 5) + d];
        a0 *= (1.f/SEQ);
        a0 += __shfl_xor(a0, 32);
        if (lane < 32)
            out[((size_t)mrow << 8) + (h << 5) + d] = __float2bfloat16(a0);
    }
}

// ---------------------------------------------------------------------------
extern "C" void kernel_launch(void* const* d_in, const int* in_sizes, int n_in,
                              void* d_out, int out_size, void* d_ws, size_t ws_size,
                              hipStream_t stream)
{
    const float* x    = (const float*)d_in[0];
    const void*  mask = d_in[1];
    const float* ln1g = (const float*)d_in[2];
    const float* ln1b = (const float*)d_in[3];
    const float* ln2g = (const float*)d_in[4];
    const float* ln2b = (const float*)d_in[5];
    const float* Wq   = (const float*)d_in[6];
    const float* bq   = (const float*)d_in[7];
    const float* Wk   = (const float*)d_in[8];
    const float* bk   = (const float*)d_in[9];
    const float* Wv   = (const float*)d_in[10];
    const float* bv   = (const float*)d_in[11];
    const float* Wo   = (const float*)d_in[12];
    const float* bo   = (const float*)d_in[13];
    const float* W1   = (const float*)d_in[14];
    const float* b1   = (const float*)d_in[15];
    const float* W2   = (const float*)d_in[16];
    const float* b2   = (const float*)d_in[17];

    // Workspace map (~35.6 MB), stream-ordered aliasing audited:
    //   idx (dead after attn) -> hbuf ; nx (dead after QKV gemm) -> attn_b ;
    //   qb (dead after attn) -> nx2
    char* w = (char*)d_ws;
    unsigned* flag      = (unsigned*)(w);
    int* counts         = (int*)(w + 1024);
    unsigned short* idx = (unsigned short*)(w + 32768);
    __hip_bfloat16* hbuf = (__hip_bfloat16*)(w + 32768);          // alias of idx
    char* base = w + 32768 + ((size_t)16 << 20);
    __hip_bfloat16* nx     = (__hip_bfloat16*)(base);             // 2 MB
    __hip_bfloat16* attn_b = nx;                                  // alias of nx
    float* qb   = (float*)(base + ((size_t)2 << 20));             // 4 MB
    __hip_bfloat16* nx2 = (__hip_bfloat16*)qb;                    // alias of qb
    float* kb   = qb + (size_t)MROWS * HID;                       // 4 MB
    float* vbuf = kb + (size_t)MROWS * HID;                       // 4 MB
    float* x1   = vbuf + (size_t)MROWS * HID;                     // 4 MB
    __hip_bfloat16* wts = (__hip_bfloat16*)(x1 + (size_t)MROWS * HID);
    __hip_bfloat16* Wtqkv = wts;                                  // [768][256]
    __hip_bfloat16* Wto   = Wtqkv + 196608;                       // [256][256]
    __hip_bfloat16* Wt1   = Wto + 65536;                          // [1024][256]
    __hip_bfloat16* Wt2   = Wt1 + 262144;                         // [256][1024]
    float* ob   = (float*)d_out;

    hipMemsetAsync(flag, 0, 4, stream);
    detect_mask<<<1024, 256, 0, stream>>>((const unsigned*)mask, flag);
    build_idx<<<MROWS, 256, 0, stream>>>(mask, flag, counts, idx);
    tconv_all<<<768, 256, 0, stream>>>(Wq, Wk, Wv, Wo, W1, W2, Wtqkv, Wto, Wt1, Wt2);
    ln_wave<<<MROWS/4, 256, 0, stream>>>(x, ln1g, ln1b, nx);
    gemm_qkv<<<dim3(64,12), 256, 0, stream>>>(nx, Wtqkv, bq, bk, bv, qb, kb, vbuf);
    attn_sparse<<<(BATCH*HEADS*SEQ)/4, 256, 0, stream>>>(qb, kb, vbuf, idx, counts, attn_b);
    gemm_mfma<256,1><<<dim3(64,4), 256, 0, stream>>>(attn_b, Wto, bo, x, x1, nullptr, HID);
    ln_wave<<<MROWS/4, 256, 0, stream>>>(x1, ln2g, ln2b, nx2);
    gemm_mfma<256,2><<<dim3(64,16), 256, 0, stream>>>(nx2, Wt1, b1, nullptr, nullptr, hbuf, 4*HID);
    gemm_mfma<1024,1><<<dim3(64,4), 256, 0, stream>>>(hbuf, Wt2, b2, x1, ob, nullptr, HID);
}